// Round 1
// baseline (232.981 us; speedup 1.0000x reference)
//
#include <hip/hip_runtime.h>

// GCN forward: direct-scatter fixed-stride-64 edge slabs + MFMA GEMMs (bf16,
// fp32 accum) + gather aggregation with vector-preloaded edge ids.
// x1 == x2 (dropout identity) => single branch; output projection folded into
// layer-2 weights:
//   W2' = W2 @ (linW_top + linW_bot),  b' = b2 @ (linW_top+linW_bot) + linb
//   h1s[i]  = inv[i] * (x @ W1)[i]                       (bf16, MFMA)
//   agg1[i] = relu( inv[i]*(sum_{N+(i)} h1s[s]) + b1 )   (bf16 out)
//   h2p[i]  = inv[i] * (agg1 @ W2')[i]                   (bf16, MFMA)
//   out     = log_softmax( inv[i]*(sum_{N+(i)} h2p[s]) + b' )
// Edge build: ONE pass — pos = atomicAdd(cnt[dst]); ebuf[dst*64+pos] = src.
// Max in-degree of the Binomial(800K, 1/50K) graph is ~35-40 (12 sigma to
// reach 64) so the 64-entry slab never overflows; inv = rsqrt(cnt+1) is
// recomputed inline from cnt everywhere (same rsqrtf -> identical values).

#define CIN  128
#define CHID 128
#define COUT 64
#define DCAP 64              // per-node edge slab capacity

typedef short v8s __attribute__((ext_vector_type(8)));
typedef float v4f __attribute__((ext_vector_type(4)));

static __device__ __forceinline__ unsigned short f2bf(float f) {
    unsigned int u = __float_as_uint(f);
    unsigned int r = (u + 0x7fffu + ((u >> 16) & 1u)) >> 16;  // RNE
    return (unsigned short)r;
}
static __device__ __forceinline__ float bf2f(unsigned short v) {
    return __uint_as_float(((unsigned int)v) << 16);
}

// ---------------- fused weight prep + cnt zeroing ----------------
// Blocks 0..127: Wt1 row j=b, plus (t<64) Wt2 row r=b of W2' = W2@Wsum (bf16^T).
// Block 128: (t<64) bp = b2 @ Wsum + linb.
// Blocks 129..: zero cnt[n] via int4 stores.
__global__ __launch_bounds__(128) void wprep_kernel(const float* __restrict__ W1,
                                                    const float* __restrict__ W2,
                                                    const float* __restrict__ b2,
                                                    const float* __restrict__ linW,
                                                    const float* __restrict__ linb,
                                                    unsigned short* __restrict__ Wt1,
                                                    unsigned short* __restrict__ Wt2,
                                                    float* __restrict__ bp,
                                                    int* __restrict__ cnt, int n) {
    int b = blockIdx.x;
    int t = threadIdx.x;
    if (b < CHID) {
        Wt1[b * CIN + t] = f2bf(W1[t * CHID + b]);
        if (t < COUT) {
            float acc = 0.f;
#pragma unroll 8
            for (int k = 0; k < COUT; ++k) {
                float wsv = linW[k * COUT + t] + linW[(k + COUT) * COUT + t];
                acc = fmaf(W2[b * COUT + k], wsv, acc);
            }
            Wt2[t * CHID + b] = f2bf(acc);
        }
    } else if (b == CHID) {
        if (t < COUT) {
            float acc = 0.f;
#pragma unroll 8
            for (int k = 0; k < COUT; ++k) {
                float wsv = linW[k * COUT + t] + linW[(k + COUT) * COUT + t];
                acc = fmaf(b2[k], wsv, acc);
            }
            bp[t] = acc + linb[t];
        }
    } else {
        int i4 = (b - CHID - 1) * 128 + t;   // int4 index
        int base = i4 * 4;
        if (base + 3 < n) {
            ((int4*)cnt)[i4] = make_int4(0, 0, 0, 0);
        } else if (base < n) {
            for (int j = base; j < n; ++j) cnt[j] = 0;
        }
    }
}

// ---------------- direct-scatter edge slab build ----------------
__global__ __launch_bounds__(256) void scatter_kernel(const int* __restrict__ src,
                                                      const int* __restrict__ dst,
                                                      int* __restrict__ cnt,
                                                      int* __restrict__ ebuf, int E) {
    int e = blockIdx.x * 256 + threadIdx.x;
    if (e >= E) return;
    int s = src[e];
    int d = dst[e];
    int pos = atomicAdd(&cnt[d], 1);
    if (pos < DCAP) ebuf[(d << 6) + pos] = s;   // overflow prob ~1e-13: drop-guard
}

// ---------------- MFMA GEMM: H[i] = inv[i] * (A @ Wt^T)[i], bf16 out ----------
template <int NOUT, bool A_BF16>
__global__ __launch_bounds__(256) void gemm_mfma(const void* __restrict__ Aptr,
                                                 const unsigned short* __restrict__ Wt,
                                                 const int* __restrict__ cnt,
                                                 unsigned short* __restrict__ H, int n) {
    constexpr int NCT = NOUT / 16;
    int lane = threadIdx.x & 63;
    int wave = threadIdx.x >> 6;
    int quad = lane >> 4, r16 = lane & 15;
    int row0 = (blockIdx.x * 4 + wave) * 16;
    if (row0 >= n) return;
    int arow = row0 + r16;
    if (arow >= n) arow = n - 1;  // clamp (safe: result masked by orow<n)

    v4f acc[NCT];
#pragma unroll
    for (int c = 0; c < NCT; ++c) acc[c] = (v4f){0.f, 0.f, 0.f, 0.f};

#pragma unroll
    for (int kc = 0; kc < 4; ++kc) {
        v8s af;
        if (A_BF16) {
            const unsigned short* A = (const unsigned short*)Aptr;
            af = *(const v8s*)(A + (size_t)arow * 128 + kc * 32 + quad * 8);
        } else {
            const float* A = (const float*)Aptr;
            const float4* ap = (const float4*)(A + (size_t)arow * 128 + kc * 32 + quad * 8);
            float4 a0 = ap[0], a1 = ap[1];
            af[0] = (short)f2bf(a0.x); af[1] = (short)f2bf(a0.y);
            af[2] = (short)f2bf(a0.z); af[3] = (short)f2bf(a0.w);
            af[4] = (short)f2bf(a1.x); af[5] = (short)f2bf(a1.y);
            af[6] = (short)f2bf(a1.z); af[7] = (short)f2bf(a1.w);
        }
#pragma unroll
        for (int ct = 0; ct < NCT; ++ct) {
            v8s bf = *(const v8s*)(Wt + (size_t)(ct * 16 + r16) * 128 + kc * 32 + quad * 8);
            acc[ct] = __builtin_amdgcn_mfma_f32_16x16x32_bf16(af, bf, acc[ct], 0, 0, 0);
        }
    }

    // epilogue: row = quad*4 + i (C/D layout), col = ct*16 + r16
    int4 cv = *(const int4*)(cnt + row0 + quad * 4);
#pragma unroll
    for (int ct = 0; ct < NCT; ++ct) {
#pragma unroll
        for (int i = 0; i < 4; ++i) {
            int orow = row0 + quad * 4 + i;
            if (orow < n) {
                int cdeg = (i == 0) ? cv.x : (i == 1) ? cv.y : (i == 2) ? cv.z : cv.w;
                float sc = rsqrtf((float)(cdeg + 1));
                H[(size_t)orow * NOUT + ct * 16 + r16] = f2bf(acc[ct][i] * sc);
            }
        }
    }
}

// ---------------- layer-1 aggregate: wave/node, readlane edge walk ----------
__global__ __launch_bounds__(256) void agg1_kernel(const unsigned int* __restrict__ Hs,
                                                   const int* __restrict__ ebuf,
                                                   const int* __restrict__ cnt,
                                                   const float* __restrict__ bias,
                                                   unsigned int* __restrict__ outp, int n) {
    int node = __builtin_amdgcn_readfirstlane(blockIdx.x * 4 + (threadIdx.x >> 6));
    int lane = threadIdx.x & 63;
    if (node >= n) return;
    int deg = cnt[node];                             // uniform -> scalar load
    int eid = ebuf[(node << 6) + lane];              // coalesced 256B preload
    int m = deg < DCAP ? deg : DCAP;
    float ax = 0.f, ay = 0.f;
    int k = 0;
    for (; k + 4 <= m; k += 4) {
        int s0 = __builtin_amdgcn_readlane(eid, k);
        int s1 = __builtin_amdgcn_readlane(eid, k + 1);
        int s2 = __builtin_amdgcn_readlane(eid, k + 2);
        int s3 = __builtin_amdgcn_readlane(eid, k + 3);
        unsigned int u0 = Hs[(size_t)s0 * 64 + lane];
        unsigned int u1 = Hs[(size_t)s1 * 64 + lane];
        unsigned int u2 = Hs[(size_t)s2 * 64 + lane];
        unsigned int u3 = Hs[(size_t)s3 * 64 + lane];
        ax += __uint_as_float(u0 << 16);  ay += __uint_as_float(u0 & 0xffff0000u);
        ax += __uint_as_float(u1 << 16);  ay += __uint_as_float(u1 & 0xffff0000u);
        ax += __uint_as_float(u2 << 16);  ay += __uint_as_float(u2 & 0xffff0000u);
        ax += __uint_as_float(u3 << 16);  ay += __uint_as_float(u3 & 0xffff0000u);
    }
    for (; k < m; ++k) {
        int s = __builtin_amdgcn_readlane(eid, k);
        unsigned int u = Hs[(size_t)s * 64 + lane];
        ax += __uint_as_float(u << 16);
        ay += __uint_as_float(u & 0xffff0000u);
    }
    {   // self-loop term
        unsigned int u = Hs[(size_t)node * 64 + lane];
        ax += __uint_as_float(u << 16);
        ay += __uint_as_float(u & 0xffff0000u);
    }
    float wd = rsqrtf((float)(deg + 1));
    float2 bv = ((const float2*)bias)[lane];
    float ox = fmaxf(fmaf(wd, ax, bv.x), 0.f);
    float oy = fmaxf(fmaf(wd, ay, bv.y), 0.f);
    outp[(size_t)node * 64 + lane] =
        (unsigned int)f2bf(ox) | ((unsigned int)f2bf(oy) << 16);
}

// ---------------- layer-2 aggregate + bias + log_softmax (readlane walk) ------
__global__ __launch_bounds__(256) void agg2_final_kernel(const unsigned short* __restrict__ Hs,
                                                         const int* __restrict__ ebuf,
                                                         const int* __restrict__ cnt,
                                                         const float* __restrict__ bp,
                                                         float* __restrict__ outp, int n) {
    int node = __builtin_amdgcn_readfirstlane(blockIdx.x * 4 + (threadIdx.x >> 6));
    int lane = threadIdx.x & 63;
    if (node >= n) return;
    int deg = cnt[node];
    int eid = ebuf[(node << 6) + lane];
    int m = deg < DCAP ? deg : DCAP;
    float acc = 0.f;
    int k = 0;
    for (; k + 4 <= m; k += 4) {
        int s0 = __builtin_amdgcn_readlane(eid, k);
        int s1 = __builtin_amdgcn_readlane(eid, k + 1);
        int s2 = __builtin_amdgcn_readlane(eid, k + 2);
        int s3 = __builtin_amdgcn_readlane(eid, k + 3);
        float v0 = bf2f(Hs[(size_t)s0 * 64 + lane]);
        float v1 = bf2f(Hs[(size_t)s1 * 64 + lane]);
        float v2 = bf2f(Hs[(size_t)s2 * 64 + lane]);
        float v3 = bf2f(Hs[(size_t)s3 * 64 + lane]);
        acc += v0 + v1 + v2 + v3;
    }
    for (; k < m; ++k) {
        int s = __builtin_amdgcn_readlane(eid, k);
        acc += bf2f(Hs[(size_t)s * 64 + lane]);
    }
    acc += bf2f(Hs[(size_t)node * 64 + lane]);       // self-loop
    float fo = fmaf(rsqrtf((float)(deg + 1)), acc, bp[lane]);
    float mx = fo;
#pragma unroll
    for (int off = 32; off >= 1; off >>= 1) mx = fmaxf(mx, __shfl_xor(mx, off, 64));
    float ex = expf(fo - mx);
    float s = ex;
#pragma unroll
    for (int off = 32; off >= 1; off >>= 1) s += __shfl_xor(s, off, 64);
    outp[(size_t)node * COUT + lane] = fo - mx - logf(s);
}

static inline size_t align16(size_t x) { return (x + 15) & ~(size_t)15; }

extern "C" void kernel_launch(void* const* d_in, const int* in_sizes, int n_in,
                              void* d_out, int out_size, void* d_ws, size_t ws_size,
                              hipStream_t stream) {
    const float* x    = (const float*)d_in[0];
    const int*   eidx = (const int*)d_in[1];
    const float* W1   = (const float*)d_in[2];
    const float* b1   = (const float*)d_in[3];
    const float* W2   = (const float*)d_in[4];
    const float* b2   = (const float*)d_in[5];
    const float* linW = (const float*)d_in[6];
    const float* linb = (const float*)d_in[7];
    float* out = (float*)d_out;

    const int n = in_sizes[0] / CIN;   // 50000
    const int E = in_sizes[1] / 2;     // 800000
    const int* src = eidx;
    const int* dst = eidx + E;

    // ---- workspace carve-up
    char* ws = (char*)d_ws;
    size_t off = 0;
    int*   cnt = (int*)(ws + off);       off = align16(off + (size_t)n * 4);
    unsigned short* Wt1 = (unsigned short*)(ws + off); off = align16(off + (size_t)CHID * CIN * 2);
    unsigned short* Wt2 = (unsigned short*)(ws + off); off = align16(off + (size_t)COUT * CHID * 2);
    float* bp      = (float*)(ws + off); off = align16(off + (size_t)COUT * 4);
    int*   ebuf    = (int*)(ws + off);   off = align16(off + (size_t)n * DCAP * 4);
    unsigned short* h1s   = (unsigned short*)(ws + off); off = align16(off + (size_t)n * CHID * 2);
    unsigned short* agg1b = (unsigned short*)(ws + off); off = align16(off + (size_t)n * CHID * 2);
    unsigned short* h2p   = (unsigned short*)(ws + off); off = align16(off + (size_t)n * COUT * 2);

    // ---- weight prep + cnt zeroing (single launch)
    const int nz = ((n + 3) / 4 + 127) / 128;
    wprep_kernel<<<CHID + 1 + nz, 128, 0, stream>>>(W1, W2, b2, linW, linb, Wt1, Wt2, bp, cnt, n);

    // ---- edge slab build: one direct-scatter pass
    scatter_kernel<<<(E + 255) / 256, 256, 0, stream>>>(src, dst, cnt, ebuf, E);

    // ---- layer 1: MFMA GEMM + gather-aggregate
    gemm_mfma<CHID, false><<<(n + 63) / 64, 256, 0, stream>>>(x, Wt1, cnt, h1s, n);
    agg1_kernel<<<(n + 3) / 4, 256, 0, stream>>>((const unsigned int*)h1s, ebuf, cnt, b1,
                                                 (unsigned int*)agg1b, n);

    // ---- layer 2: MFMA GEMM (bf16 A) + final
    gemm_mfma<COUT, true><<<(n + 63) / 64, 256, 0, stream>>>(agg1b, Wt2, cnt, h2p, n);
    agg2_final_kernel<<<(n + 3) / 4, 256, 0, stream>>>(h2p, ebuf, cnt, bp, out, n);
}

// Round 2
// 210.682 us; speedup vs baseline: 1.1058x; 1.1058x over previous
//
#include <hip/hip_runtime.h>

// GCN forward: fixed-capacity bucket-sort CSR + MFMA GEMMs (bf16, fp32 accum)
// + gather aggregation with vector-preloaded edge ids (readlane walk, ILP-8).
// x1 == x2 (dropout identity) => single branch; output projection folded into
// layer-2 weights:
//   W2' = W2 @ (linW_top + linW_bot),  b' = b2 @ (linW_top+linW_bot) + linb
//   h1s[i]  = inv[i] * (x @ W1)[i]                       (bf16, MFMA)
//   agg1[i] = relu( inv[i]*(sum_{N+(i)} h1s[s]) + b1 )   (bf16 out)
//   h2p[i]  = inv[i] * (agg1 @ W2')[i]                   (bf16, MFMA)
//   out     = log_softmax( inv[i]*(sum_{N+(i)} h2p[s]) + b' )
// Buckets: 256 dst nodes each, FIXED capacity 8192 (mean 4096, Poisson sigma
// 64 -> overflow prob ~0). Assumes n <= 65536 (src ids pack in 16 bits).
// NOTE (round-1 post-mortem): single-pass direct scatter (random 4B writes +
// 800K global atomics) measured 52us vs ~34us for this two-pass build — the
// bucket-localized writes are the point. Do not "simplify" this again.

#define CIN  128
#define CHID 128
#define COUT 64
#define BCAP_SH 13           // bucket capacity 8192 entries
#define BCAP    (1 << BCAP_SH)
#define BINCHUNK 2048        // small chunks -> 391 blocks -> latency hiding

typedef short v8s __attribute__((ext_vector_type(8)));
typedef float v4f __attribute__((ext_vector_type(4)));

static __device__ __forceinline__ unsigned short f2bf(float f) {
    unsigned int u = __float_as_uint(f);
    unsigned int r = (u + 0x7fffu + ((u >> 16) & 1u)) >> 16;  // RNE
    return (unsigned short)r;
}
static __device__ __forceinline__ float bf2f(unsigned short v) {
    return __uint_as_float(((unsigned int)v) << 16);
}

// ---------------- bin edges into fixed-cap bucket regions ----------------
// Bucket b's region is [b*BCAP, (b+1)*BCAP): bases are compile-time.
__global__ __launch_bounds__(256) void bin_kernel(const int* __restrict__ src,
                                                  const int* __restrict__ dst,
                                                  int* __restrict__ bcursor,
                                                  unsigned int* __restrict__ binned, int E) {
    __shared__ int h[256];
    __shared__ int base[256];
    int t = threadIdx.x;
    h[t] = 0;
    __syncthreads();
    int e0 = blockIdx.x * BINCHUNK;
    int e1 = e0 + BINCHUNK; if (e1 > E) e1 = E;
    for (int e = e0 + t; e < e1; e += 256)
        atomicAdd(&h[dst[e] >> 8], 1);
    __syncthreads();
    int c = h[t];
    base[t] = (t << BCAP_SH) + (c ? atomicAdd(&bcursor[t], c) : 0);
    __syncthreads();
    h[t] = 0;
    __syncthreads();
    for (int e = e0 + t; e < e1; e += 256) {
        int d = dst[e];
        int b = d >> 8;
        int pos = base[b] + atomicAdd(&h[b], 1);
        binned[pos] = (unsigned int)src[e] | (((unsigned int)d & 255u) << 16);
    }
}

// ---------------- per-bucket CSR build (deg->inv, rowpair, ebuf), 512 thr ------
__global__ __launch_bounds__(512) void csr_kernel(const unsigned int* __restrict__ binned,
                                                  const int* __restrict__ bcursor,
                                                  int2* __restrict__ rowpair,
                                                  float* __restrict__ inv,
                                                  int* __restrict__ ebuf, int n) {
    __shared__ int h[256];
    __shared__ int s[256];
    int b = blockIdx.x;
    int t = threadIdx.x;
    int base = b << BCAP_SH;
    int cnt  = bcursor[b];
    if (t < 256) h[t] = 0;
    __syncthreads();
    // phase 1: per-dst hist (512-wide)
    for (int i = t; i < cnt; i += 512)
        atomicAdd(&h[binned[base + i] >> 16], 1);
    __syncthreads();
    int myc = (t < 256) ? h[t] : 0;
    if (t < 256) s[t] = myc;
    __syncthreads();
    // phase 2: scan (first 256 threads; all threads hit barriers)
    for (int off = 1; off < 256; off <<= 1) {
        int u = (t >= off && t < 256) ? s[t - off] : 0;
        __syncthreads();
        if (t < 256) s[t] += u;
        __syncthreads();
    }
    if (t < 256) {
        int excl = s[t] - myc;
        int node = (b << 8) + t;
        if (node < n) {
            rowpair[node] = make_int2(base + excl, base + excl + myc);
            inv[node] = rsqrtf((float)(myc + 1));  // +1: self-loop
        }
        h[t] = base + excl;  // cursor
    }
    __syncthreads();
    // phase 3: scatter src ids (512-wide)
    for (int i = t; i < cnt; i += 512) {
        unsigned int v = binned[base + i];
        int pos = atomicAdd(&h[v >> 16], 1);
        ebuf[pos] = (int)(v & 0xffffu);
    }
}

// ---------------- fused weight prep + bcursor zeroing ----------------
// Blocks 0..127: Wt1 row j=b, plus (t<64) Wt2 row r=b of W2' = W2@Wsum (bf16^T).
// Block 128: (t<64) bp = b2 @ Wsum + linb; all 128 threads zero bcursor.
__global__ __launch_bounds__(128) void wprep_kernel(const float* __restrict__ W1,
                                                    const float* __restrict__ W2,
                                                    const float* __restrict__ b2,
                                                    const float* __restrict__ linW,
                                                    const float* __restrict__ linb,
                                                    unsigned short* __restrict__ Wt1,
                                                    unsigned short* __restrict__ Wt2,
                                                    float* __restrict__ bp,
                                                    int* __restrict__ bcursor) {
    int b = blockIdx.x;   // 0..128
    int t = threadIdx.x;  // 0..127
    if (b < CHID) {
        Wt1[b * CIN + t] = f2bf(W1[t * CHID + b]);
        if (t < COUT) {
            float acc = 0.f;
#pragma unroll 8
            for (int k = 0; k < COUT; ++k) {
                float wsv = linW[k * COUT + t] + linW[(k + COUT) * COUT + t];
                acc = fmaf(W2[b * COUT + k], wsv, acc);
            }
            Wt2[t * CHID + b] = f2bf(acc);
        }
    } else {
        bcursor[t] = 0;
        bcursor[128 + t] = 0;
        if (t < COUT) {
            float acc = 0.f;
#pragma unroll 8
            for (int k = 0; k < COUT; ++k) {
                float wsv = linW[k * COUT + t] + linW[(k + COUT) * COUT + t];
                acc = fmaf(b2[k], wsv, acc);
            }
            bp[t] = acc + linb[t];
        }
    }
}

// ---------------- MFMA GEMM: H[i] = inv[i] * (A @ Wt^T)[i], bf16 out ----------
template <int NOUT, bool A_BF16>
__global__ __launch_bounds__(256) void gemm_mfma(const void* __restrict__ Aptr,
                                                 const unsigned short* __restrict__ Wt,
                                                 const float* __restrict__ inv,
                                                 unsigned short* __restrict__ H, int n) {
    constexpr int NCT = NOUT / 16;
    int lane = threadIdx.x & 63;
    int wave = threadIdx.x >> 6;
    int quad = lane >> 4, r16 = lane & 15;
    int row0 = (blockIdx.x * 4 + wave) * 16;
    if (row0 >= n) return;
    int arow = row0 + r16;
    if (arow >= n) arow = n - 1;  // clamp (safe: result masked by orow<n)

    v4f acc[NCT];
#pragma unroll
    for (int c = 0; c < NCT; ++c) acc[c] = (v4f){0.f, 0.f, 0.f, 0.f};

#pragma unroll
    for (int kc = 0; kc < 4; ++kc) {
        v8s af;
        if (A_BF16) {
            const unsigned short* A = (const unsigned short*)Aptr;
            af = *(const v8s*)(A + (size_t)arow * 128 + kc * 32 + quad * 8);
        } else {
            const float* A = (const float*)Aptr;
            const float4* ap = (const float4*)(A + (size_t)arow * 128 + kc * 32 + quad * 8);
            float4 a0 = ap[0], a1 = ap[1];
            af[0] = (short)f2bf(a0.x); af[1] = (short)f2bf(a0.y);
            af[2] = (short)f2bf(a0.z); af[3] = (short)f2bf(a0.w);
            af[4] = (short)f2bf(a1.x); af[5] = (short)f2bf(a1.y);
            af[6] = (short)f2bf(a1.z); af[7] = (short)f2bf(a1.w);
        }
#pragma unroll
        for (int ct = 0; ct < NCT; ++ct) {
            v8s bf = *(const v8s*)(Wt + (size_t)(ct * 16 + r16) * 128 + kc * 32 + quad * 8);
            acc[ct] = __builtin_amdgcn_mfma_f32_16x16x32_bf16(af, bf, acc[ct], 0, 0, 0);
        }
    }

    // epilogue: row = quad*4 + i (C/D layout), col = ct*16 + r16
    float4 iv = ((const float4*)(inv + row0))[quad];
#pragma unroll
    for (int ct = 0; ct < NCT; ++ct) {
#pragma unroll
        for (int i = 0; i < 4; ++i) {
            int orow = row0 + quad * 4 + i;
            if (orow < n) {
                float sc = (i == 0) ? iv.x : (i == 1) ? iv.y : (i == 2) ? iv.z : iv.w;
                H[(size_t)orow * NOUT + ct * 16 + r16] = f2bf(acc[ct][i] * sc);
            }
        }
    }
}

// ---------------- layer-1 aggregate: wave/node, readlane edge walk (ILP-8) ----
__global__ void agg1_kernel(const unsigned int* __restrict__ Hs, const int* __restrict__ ebuf,
                            const int2* __restrict__ rowpair, const float* __restrict__ inv,
                            const float* __restrict__ bias, unsigned int* __restrict__ outp,
                            int n) {
    int node = __builtin_amdgcn_readfirstlane(blockIdx.x * 4 + (threadIdx.x >> 6));
    int lane = threadIdx.x & 63;
    if (node >= n) return;
    int2 rp = rowpair[node];                         // uniform -> s_load_dwordx2
    int beg = rp.x, len = rp.y - rp.x;
    int eid = ebuf[beg + lane];                      // coalesced preload
    // self-loop load issued first: overlaps with the walk
    unsigned int usl = Hs[(size_t)node * 64 + lane];
    int m = len < 64 ? len : 64;
    float ax = 0.f, ay = 0.f;
    int k = 0;
    for (; k + 8 <= m; k += 8) {                     // 8 loads in flight
        int s0 = __builtin_amdgcn_readlane(eid, k);
        int s1 = __builtin_amdgcn_readlane(eid, k + 1);
        int s2 = __builtin_amdgcn_readlane(eid, k + 2);
        int s3 = __builtin_amdgcn_readlane(eid, k + 3);
        int s4 = __builtin_amdgcn_readlane(eid, k + 4);
        int s5 = __builtin_amdgcn_readlane(eid, k + 5);
        int s6 = __builtin_amdgcn_readlane(eid, k + 6);
        int s7 = __builtin_amdgcn_readlane(eid, k + 7);
        unsigned int u0 = Hs[(size_t)s0 * 64 + lane];
        unsigned int u1 = Hs[(size_t)s1 * 64 + lane];
        unsigned int u2 = Hs[(size_t)s2 * 64 + lane];
        unsigned int u3 = Hs[(size_t)s3 * 64 + lane];
        unsigned int u4 = Hs[(size_t)s4 * 64 + lane];
        unsigned int u5 = Hs[(size_t)s5 * 64 + lane];
        unsigned int u6 = Hs[(size_t)s6 * 64 + lane];
        unsigned int u7 = Hs[(size_t)s7 * 64 + lane];
        ax += __uint_as_float(u0 << 16);  ay += __uint_as_float(u0 & 0xffff0000u);
        ax += __uint_as_float(u1 << 16);  ay += __uint_as_float(u1 & 0xffff0000u);
        ax += __uint_as_float(u2 << 16);  ay += __uint_as_float(u2 & 0xffff0000u);
        ax += __uint_as_float(u3 << 16);  ay += __uint_as_float(u3 & 0xffff0000u);
        ax += __uint_as_float(u4 << 16);  ay += __uint_as_float(u4 & 0xffff0000u);
        ax += __uint_as_float(u5 << 16);  ay += __uint_as_float(u5 & 0xffff0000u);
        ax += __uint_as_float(u6 << 16);  ay += __uint_as_float(u6 & 0xffff0000u);
        ax += __uint_as_float(u7 << 16);  ay += __uint_as_float(u7 & 0xffff0000u);
    }
    for (; k + 4 <= m; k += 4) {
        int s0 = __builtin_amdgcn_readlane(eid, k);
        int s1 = __builtin_amdgcn_readlane(eid, k + 1);
        int s2 = __builtin_amdgcn_readlane(eid, k + 2);
        int s3 = __builtin_amdgcn_readlane(eid, k + 3);
        unsigned int u0 = Hs[(size_t)s0 * 64 + lane];
        unsigned int u1 = Hs[(size_t)s1 * 64 + lane];
        unsigned int u2 = Hs[(size_t)s2 * 64 + lane];
        unsigned int u3 = Hs[(size_t)s3 * 64 + lane];
        ax += __uint_as_float(u0 << 16);  ay += __uint_as_float(u0 & 0xffff0000u);
        ax += __uint_as_float(u1 << 16);  ay += __uint_as_float(u1 & 0xffff0000u);
        ax += __uint_as_float(u2 << 16);  ay += __uint_as_float(u2 & 0xffff0000u);
        ax += __uint_as_float(u3 << 16);  ay += __uint_as_float(u3 & 0xffff0000u);
    }
    for (; k < m; ++k) {
        int s = __builtin_amdgcn_readlane(eid, k);
        unsigned int u = Hs[(size_t)s * 64 + lane];
        ax += __uint_as_float(u << 16);
        ay += __uint_as_float(u & 0xffff0000u);
    }
    for (; k < len; ++k) {                           // deg > 64 fallback (rare)
        int s = ebuf[beg + k];
        unsigned int u = Hs[(size_t)s * 64 + lane];
        ax += __uint_as_float(u << 16);
        ay += __uint_as_float(u & 0xffff0000u);
    }
    ax += __uint_as_float(usl << 16);                // self-loop term
    ay += __uint_as_float(usl & 0xffff0000u);
    float wd = inv[node];
    float2 bv = ((const float2*)bias)[lane];
    float ox = fmaxf(fmaf(wd, ax, bv.x), 0.f);
    float oy = fmaxf(fmaf(wd, ay, bv.y), 0.f);
    outp[(size_t)node * 64 + lane] =
        (unsigned int)f2bf(ox) | ((unsigned int)f2bf(oy) << 16);
}

// ---------------- layer-2 aggregate + bias + log_softmax (ILP-8 walk) --------
__global__ void agg2_final_kernel(const unsigned short* __restrict__ Hs,
                                  const int* __restrict__ ebuf, const int2* __restrict__ rowpair,
                                  const float* __restrict__ inv, const float* __restrict__ bp,
                                  float* __restrict__ outp, int n) {
    int node = __builtin_amdgcn_readfirstlane(blockIdx.x * 4 + (threadIdx.x >> 6));
    int lane = threadIdx.x & 63;
    if (node >= n) return;
    int2 rp = rowpair[node];
    int beg = rp.x, len = rp.y - rp.x;
    int eid = ebuf[beg + lane];
    float vsl = bf2f(Hs[(size_t)node * 64 + lane]); // self-loop, issued early
    int m = len < 64 ? len : 64;
    float acc = 0.f;
    int k = 0;
    for (; k + 8 <= m; k += 8) {                     // 8 loads in flight
        int s0 = __builtin_amdgcn_readlane(eid, k);
        int s1 = __builtin_amdgcn_readlane(eid, k + 1);
        int s2 = __builtin_amdgcn_readlane(eid, k + 2);
        int s3 = __builtin_amdgcn_readlane(eid, k + 3);
        int s4 = __builtin_amdgcn_readlane(eid, k + 4);
        int s5 = __builtin_amdgcn_readlane(eid, k + 5);
        int s6 = __builtin_amdgcn_readlane(eid, k + 6);
        int s7 = __builtin_amdgcn_readlane(eid, k + 7);
        float v0 = bf2f(Hs[(size_t)s0 * 64 + lane]);
        float v1 = bf2f(Hs[(size_t)s1 * 64 + lane]);
        float v2 = bf2f(Hs[(size_t)s2 * 64 + lane]);
        float v3 = bf2f(Hs[(size_t)s3 * 64 + lane]);
        float v4 = bf2f(Hs[(size_t)s4 * 64 + lane]);
        float v5 = bf2f(Hs[(size_t)s5 * 64 + lane]);
        float v6 = bf2f(Hs[(size_t)s6 * 64 + lane]);
        float v7 = bf2f(Hs[(size_t)s7 * 64 + lane]);
        acc += ((v0 + v1) + (v2 + v3)) + ((v4 + v5) + (v6 + v7));
    }
    for (; k + 4 <= m; k += 4) {
        int s0 = __builtin_amdgcn_readlane(eid, k);
        int s1 = __builtin_amdgcn_readlane(eid, k + 1);
        int s2 = __builtin_amdgcn_readlane(eid, k + 2);
        int s3 = __builtin_amdgcn_readlane(eid, k + 3);
        float v0 = bf2f(Hs[(size_t)s0 * 64 + lane]);
        float v1 = bf2f(Hs[(size_t)s1 * 64 + lane]);
        float v2 = bf2f(Hs[(size_t)s2 * 64 + lane]);
        float v3 = bf2f(Hs[(size_t)s3 * 64 + lane]);
        acc += (v0 + v1) + (v2 + v3);
    }
    for (; k < m; ++k) {
        int s = __builtin_amdgcn_readlane(eid, k);
        acc += bf2f(Hs[(size_t)s * 64 + lane]);
    }
    for (; k < len; ++k) {                           // deg > 64 fallback
        acc += bf2f(Hs[(size_t)ebuf[beg + k] * 64 + lane]);
    }
    acc += vsl;                                      // self-loop
    float fo = fmaf(inv[node], acc, bp[lane]);
    float mx = fo;
#pragma unroll
    for (int off = 32; off >= 1; off >>= 1) mx = fmaxf(mx, __shfl_xor(mx, off, 64));
    float ex = expf(fo - mx);
    float s = ex;
#pragma unroll
    for (int off = 32; off >= 1; off >>= 1) s += __shfl_xor(s, off, 64);
    outp[(size_t)node * COUT + lane] = fo - mx - logf(s);
}

static inline size_t align16(size_t x) { return (x + 15) & ~(size_t)15; }

extern "C" void kernel_launch(void* const* d_in, const int* in_sizes, int n_in,
                              void* d_out, int out_size, void* d_ws, size_t ws_size,
                              hipStream_t stream) {
    const float* x    = (const float*)d_in[0];
    const int*   eidx = (const int*)d_in[1];
    const float* W1   = (const float*)d_in[2];
    const float* b1   = (const float*)d_in[3];
    const float* W2   = (const float*)d_in[4];
    const float* b2   = (const float*)d_in[5];
    const float* linW = (const float*)d_in[6];
    const float* linb = (const float*)d_in[7];
    float* out = (float*)d_out;

    const int n = in_sizes[0] / CIN;   // 50000
    const int E = in_sizes[1] / 2;     // 800000
    const int* src = eidx;
    const int* dst = eidx + E;
    const int NBKT = (n + 255) >> 8;   // 196

    // ---- workspace carve-up
    char* ws = (char*)d_ws;
    size_t off = 0;
    int2*  rowpair = (int2*)(ws + off);  off = align16(off + (size_t)n * 8);
    float* inv     = (float*)(ws + off); off = align16(off + (size_t)n * 4);
    int*   bcursor = (int*)(ws + off);   off = align16(off + 256 * 4);
    unsigned short* Wt1 = (unsigned short*)(ws + off); off = align16(off + (size_t)CHID * CIN * 2);
    unsigned short* Wt2 = (unsigned short*)(ws + off); off = align16(off + (size_t)COUT * CHID * 2);
    float* bp      = (float*)(ws + off); off = align16(off + (size_t)COUT * 4);
    unsigned int* binned = (unsigned int*)(ws + off); off = align16(off + (size_t)256 * BCAP * 4);
    int*   ebuf    = (int*)(ws + off);   off = align16(off + (size_t)256 * BCAP * 4);
    unsigned short* h1s   = (unsigned short*)(ws + off); off = align16(off + (size_t)n * CHID * 2);
    unsigned short* agg1b = (unsigned short*)(ws + off); off = align16(off + (size_t)n * CHID * 2);
    unsigned short* h2p   = (unsigned short*)(ws + off); off = align16(off + (size_t)n * COUT * 2);

    // ---- weight prep + bcursor zeroing (single launch, replaces memset)
    wprep_kernel<<<CHID + 1, 128, 0, stream>>>(W1, W2, b2, linW, linb, Wt1, Wt2, bp, bcursor);

    // ---- CSR build: bin (fixed-cap regions) -> per-bucket CSR
    bin_kernel<<<(E + BINCHUNK - 1) / BINCHUNK, 256, 0, stream>>>(src, dst, bcursor, binned, E);
    csr_kernel<<<NBKT, 512, 0, stream>>>(binned, bcursor, rowpair, inv, ebuf, n);

    // ---- layer 1: MFMA GEMM + gather-aggregate
    gemm_mfma<CHID, false><<<(n + 63) / 64, 256, 0, stream>>>(x, Wt1, inv, h1s, n);
    agg1_kernel<<<(n + 3) / 4, 256, 0, stream>>>((const unsigned int*)h1s, ebuf, rowpair, inv, b1,
                                                 (unsigned int*)agg1b, n);

    // ---- layer 2: MFMA GEMM (bf16 A) + final
    gemm_mfma<COUT, true><<<(n + 63) / 64, 256, 0, stream>>>(agg1b, Wt2, inv, h2p, n);
    agg2_final_kernel<<<(n + 3) / 4, 256, 0, stream>>>(h2p, ebuf, rowpair, inv, bp, out, n);
}

// Round 3
// 209.034 us; speedup vs baseline: 1.1146x; 1.0079x over previous
//
#include <hip/hip_runtime.h>

// GCN forward: fixed-capacity bucket-sort CSR + MFMA GEMMs (bf16, fp32 accum)
// + gather aggregation (2-edges-per-wave readlane walk, ILP-8 => 16 edges in
// flight). gemm2 is FUSED into agg1 via an LDS tile (16 nodes/block).
//   W2' = W2 @ (linW_top + linW_bot),  b' = b2 @ (linW_top+linW_bot) + linb
//   h1s[i]  = inv[i] * (x @ W1)[i]                       (bf16, MFMA)
//   agg1[i] = relu( inv[i]*(sum_{N+(i)} h1s[s]) + b1 )   (bf16, in LDS)
//   h2p[i]  = inv[i] * (agg1 @ W2')[i]                   (bf16, MFMA in same kernel)
//   out     = log_softmax( inv[i]*(sum_{N+(i)} h2p[s]) + b' )
// Buckets: 256 dst nodes each, FIXED capacity 8192. n <= 65536 (16-bit src).
// NOTE (round-1 post-mortem): single-pass direct scatter (random 4B writes +
// 800K global atomics) measured 52us vs ~34us for this two-pass build — the
// bucket-localized writes are the point. Do not "simplify" this again.

#define CIN  128
#define CHID 128
#define COUT 64
#define BCAP_SH 13           // bucket capacity 8192 entries
#define BCAP    (1 << BCAP_SH)
#define BINCHUNK 2048        // small chunks -> 391 blocks -> latency hiding

typedef short v8s __attribute__((ext_vector_type(8)));
typedef float v4f __attribute__((ext_vector_type(4)));

static __device__ __forceinline__ unsigned short f2bf(float f) {
    unsigned int u = __float_as_uint(f);
    unsigned int r = (u + 0x7fffu + ((u >> 16) & 1u)) >> 16;  // RNE
    return (unsigned short)r;
}
static __device__ __forceinline__ float bf2f(unsigned short v) {
    return __uint_as_float(((unsigned int)v) << 16);
}
static __device__ __forceinline__ float bflo(unsigned int u) {
    return __uint_as_float(u << 16);
}
static __device__ __forceinline__ float bfhi(unsigned int u) {
    return __uint_as_float(u & 0xffff0000u);
}

// ---------------- bin edges into fixed-cap bucket regions ----------------
__global__ __launch_bounds__(256) void bin_kernel(const int* __restrict__ src,
                                                  const int* __restrict__ dst,
                                                  int* __restrict__ bcursor,
                                                  unsigned int* __restrict__ binned, int E) {
    __shared__ int h[256];
    __shared__ int base[256];
    int t = threadIdx.x;
    h[t] = 0;
    __syncthreads();
    int e0 = blockIdx.x * BINCHUNK;
    int e1 = e0 + BINCHUNK; if (e1 > E) e1 = E;
    for (int e = e0 + t; e < e1; e += 256)
        atomicAdd(&h[dst[e] >> 8], 1);
    __syncthreads();
    int c = h[t];
    base[t] = (t << BCAP_SH) + (c ? atomicAdd(&bcursor[t], c) : 0);
    __syncthreads();
    h[t] = 0;
    __syncthreads();
    for (int e = e0 + t; e < e1; e += 256) {
        int d = dst[e];
        int b = d >> 8;
        int pos = base[b] + atomicAdd(&h[b], 1);
        binned[pos] = (unsigned int)src[e] | (((unsigned int)d & 255u) << 16);
    }
}

// ---------------- per-bucket CSR build (deg->inv, rowpair, ebuf), 512 thr ------
__global__ __launch_bounds__(512) void csr_kernel(const unsigned int* __restrict__ binned,
                                                  const int* __restrict__ bcursor,
                                                  int2* __restrict__ rowpair,
                                                  float* __restrict__ inv,
                                                  int* __restrict__ ebuf, int n) {
    __shared__ int h[256];
    __shared__ int s[256];
    int b = blockIdx.x;
    int t = threadIdx.x;
    int base = b << BCAP_SH;
    int cnt  = bcursor[b];
    if (t < 256) h[t] = 0;
    __syncthreads();
    for (int i = t; i < cnt; i += 512)
        atomicAdd(&h[binned[base + i] >> 16], 1);
    __syncthreads();
    int myc = (t < 256) ? h[t] : 0;
    if (t < 256) s[t] = myc;
    __syncthreads();
    for (int off = 1; off < 256; off <<= 1) {
        int u = (t >= off && t < 256) ? s[t - off] : 0;
        __syncthreads();
        if (t < 256) s[t] += u;
        __syncthreads();
    }
    if (t < 256) {
        int excl = s[t] - myc;
        int node = (b << 8) + t;
        if (node < n) {
            rowpair[node] = make_int2(base + excl, base + excl + myc);
            inv[node] = rsqrtf((float)(myc + 1));  // +1: self-loop
        }
        h[t] = base + excl;  // cursor
    }
    __syncthreads();
    for (int i = t; i < cnt; i += 512) {
        unsigned int v = binned[base + i];
        int pos = atomicAdd(&h[v >> 16], 1);
        ebuf[pos] = (int)(v & 0xffffu);
    }
}

// ---------------- fused weight prep + bcursor zeroing ----------------
__global__ __launch_bounds__(128) void wprep_kernel(const float* __restrict__ W1,
                                                    const float* __restrict__ W2,
                                                    const float* __restrict__ b2,
                                                    const float* __restrict__ linW,
                                                    const float* __restrict__ linb,
                                                    unsigned short* __restrict__ Wt1,
                                                    unsigned short* __restrict__ Wt2,
                                                    float* __restrict__ bp,
                                                    int* __restrict__ bcursor) {
    int b = blockIdx.x;   // 0..128
    int t = threadIdx.x;  // 0..127
    if (b < CHID) {
        Wt1[b * CIN + t] = f2bf(W1[t * CHID + b]);
        if (t < COUT) {
            float acc = 0.f;
#pragma unroll 8
            for (int k = 0; k < COUT; ++k) {
                float wsv = linW[k * COUT + t] + linW[(k + COUT) * COUT + t];
                acc = fmaf(W2[b * COUT + k], wsv, acc);
            }
            Wt2[t * CHID + b] = f2bf(acc);
        }
    } else {
        bcursor[t] = 0;
        bcursor[128 + t] = 0;
        if (t < COUT) {
            float acc = 0.f;
#pragma unroll 8
            for (int k = 0; k < COUT; ++k) {
                float wsv = linW[k * COUT + t] + linW[(k + COUT) * COUT + t];
                acc = fmaf(b2[k], wsv, acc);
            }
            bp[t] = acc + linb[t];
        }
    }
}

// ---------------- MFMA GEMM: H[i] = inv[i] * (A @ Wt^T)[i], bf16 out ----------
template <int NOUT, bool A_BF16>
__global__ __launch_bounds__(256) void gemm_mfma(const void* __restrict__ Aptr,
                                                 const unsigned short* __restrict__ Wt,
                                                 const float* __restrict__ inv,
                                                 unsigned short* __restrict__ H, int n) {
    constexpr int NCT = NOUT / 16;
    int lane = threadIdx.x & 63;
    int wave = threadIdx.x >> 6;
    int quad = lane >> 4, r16 = lane & 15;
    int row0 = (blockIdx.x * 4 + wave) * 16;
    if (row0 >= n) return;
    int arow = row0 + r16;
    if (arow >= n) arow = n - 1;

    v4f acc[NCT];
#pragma unroll
    for (int c = 0; c < NCT; ++c) acc[c] = (v4f){0.f, 0.f, 0.f, 0.f};

#pragma unroll
    for (int kc = 0; kc < 4; ++kc) {
        v8s af;
        if (A_BF16) {
            const unsigned short* A = (const unsigned short*)Aptr;
            af = *(const v8s*)(A + (size_t)arow * 128 + kc * 32 + quad * 8);
        } else {
            const float* A = (const float*)Aptr;
            const float4* ap = (const float4*)(A + (size_t)arow * 128 + kc * 32 + quad * 8);
            float4 a0 = ap[0], a1 = ap[1];
            af[0] = (short)f2bf(a0.x); af[1] = (short)f2bf(a0.y);
            af[2] = (short)f2bf(a0.z); af[3] = (short)f2bf(a0.w);
            af[4] = (short)f2bf(a1.x); af[5] = (short)f2bf(a1.y);
            af[6] = (short)f2bf(a1.z); af[7] = (short)f2bf(a1.w);
        }
#pragma unroll
        for (int ct = 0; ct < NCT; ++ct) {
            v8s bf = *(const v8s*)(Wt + (size_t)(ct * 16 + r16) * 128 + kc * 32 + quad * 8);
            acc[ct] = __builtin_amdgcn_mfma_f32_16x16x32_bf16(af, bf, acc[ct], 0, 0, 0);
        }
    }

    float4 iv = ((const float4*)(inv + row0))[quad];
#pragma unroll
    for (int ct = 0; ct < NCT; ++ct) {
#pragma unroll
        for (int i = 0; i < 4; ++i) {
            int orow = row0 + quad * 4 + i;
            if (orow < n) {
                float sc = (i == 0) ? iv.x : (i == 1) ? iv.y : (i == 2) ? iv.z : iv.w;
                H[(size_t)orow * NOUT + ct * 16 + r16] = f2bf(acc[ct][i] * sc);
            }
        }
    }
}

// ---------------- FUSED layer-1 aggregate + layer-2 GEMM ----------------
// Block = 256 thr = 4 waves = 16 nodes. Each wave aggregates 4 nodes
// (2 edges per wave-load: half-wave A reads edge k's 256B row via uint2,
// half-wave B reads edge k+1's). Rows -> LDS tile [16][128] bf16 (stride 68
// dwords, padded). Barrier, then wave w computes 16x16 col-tile w of
// agg @ W2'^T with MFMA and writes inv-scaled h2p.
__global__ __launch_bounds__(256) void agg1_gemm2_kernel(
        const unsigned int* __restrict__ Hs,      // h1s as uint [n][64]
        const int* __restrict__ ebuf,
        const int2* __restrict__ rowpair,
        const float* __restrict__ inv,
        const float* __restrict__ bias,           // b1[128]
        const unsigned short* __restrict__ Wt2,   // [64][128] bf16
        unsigned short* __restrict__ H2,          // h2p [n][64]
        int n) {
    __shared__ unsigned int tileu[16 * 68];
    const uint2* __restrict__ Hs2 = (const uint2*)Hs;  // [n][32] uint2
    int node0 = blockIdx.x * 16;
    int wid = __builtin_amdgcn_readfirstlane(threadIdx.x >> 6);
    int lane = threadIdx.x & 63;
    int l32 = lane & 31;
    bool hi = lane >= 32;

    for (int j = 0; j < 4; ++j) {
        int r = wid * 4 + j;
        int node = node0 + r;
        float a0 = 0.f, a1 = 0.f, a2 = 0.f, a3 = 0.f;
        if (node < n) {
            int2 rp = rowpair[node];
            int beg = rp.x, len = rp.y - rp.x;
            int eid = ebuf[beg + lane];
            uint2 usl = Hs2[(size_t)node * 32 + l32];     // self-loop row (early)
            int m = len < 64 ? len : 64;
            int k = 0;
            for (; k + 16 <= m; k += 16) {                // 16 edges in flight
                int sa0 = __builtin_amdgcn_readlane(eid, k);
                int sb0 = __builtin_amdgcn_readlane(eid, k + 1);
                int sa1 = __builtin_amdgcn_readlane(eid, k + 2);
                int sb1 = __builtin_amdgcn_readlane(eid, k + 3);
                int sa2 = __builtin_amdgcn_readlane(eid, k + 4);
                int sb2 = __builtin_amdgcn_readlane(eid, k + 5);
                int sa3 = __builtin_amdgcn_readlane(eid, k + 6);
                int sb3 = __builtin_amdgcn_readlane(eid, k + 7);
                int sa4 = __builtin_amdgcn_readlane(eid, k + 8);
                int sb4 = __builtin_amdgcn_readlane(eid, k + 9);
                int sa5 = __builtin_amdgcn_readlane(eid, k + 10);
                int sb5 = __builtin_amdgcn_readlane(eid, k + 11);
                int sa6 = __builtin_amdgcn_readlane(eid, k + 12);
                int sb6 = __builtin_amdgcn_readlane(eid, k + 13);
                int sa7 = __builtin_amdgcn_readlane(eid, k + 14);
                int sb7 = __builtin_amdgcn_readlane(eid, k + 15);
                uint2 u0 = Hs2[(size_t)(hi ? sb0 : sa0) * 32 + l32];
                uint2 u1 = Hs2[(size_t)(hi ? sb1 : sa1) * 32 + l32];
                uint2 u2 = Hs2[(size_t)(hi ? sb2 : sa2) * 32 + l32];
                uint2 u3 = Hs2[(size_t)(hi ? sb3 : sa3) * 32 + l32];
                uint2 u4 = Hs2[(size_t)(hi ? sb4 : sa4) * 32 + l32];
                uint2 u5 = Hs2[(size_t)(hi ? sb5 : sa5) * 32 + l32];
                uint2 u6 = Hs2[(size_t)(hi ? sb6 : sa6) * 32 + l32];
                uint2 u7 = Hs2[(size_t)(hi ? sb7 : sa7) * 32 + l32];
                a0 += bflo(u0.x); a1 += bfhi(u0.x); a2 += bflo(u0.y); a3 += bfhi(u0.y);
                a0 += bflo(u1.x); a1 += bfhi(u1.x); a2 += bflo(u1.y); a3 += bfhi(u1.y);
                a0 += bflo(u2.x); a1 += bfhi(u2.x); a2 += bflo(u2.y); a3 += bfhi(u2.y);
                a0 += bflo(u3.x); a1 += bfhi(u3.x); a2 += bflo(u3.y); a3 += bfhi(u3.y);
                a0 += bflo(u4.x); a1 += bfhi(u4.x); a2 += bflo(u4.y); a3 += bfhi(u4.y);
                a0 += bflo(u5.x); a1 += bfhi(u5.x); a2 += bflo(u5.y); a3 += bfhi(u5.y);
                a0 += bflo(u6.x); a1 += bfhi(u6.x); a2 += bflo(u6.y); a3 += bfhi(u6.y);
                a0 += bflo(u7.x); a1 += bfhi(u7.x); a2 += bflo(u7.y); a3 += bfhi(u7.y);
            }
            for (; k + 2 <= m; k += 2) {                  // pair tail
                int sa = __builtin_amdgcn_readlane(eid, k);
                int sb = __builtin_amdgcn_readlane(eid, k + 1);
                uint2 u = Hs2[(size_t)(hi ? sb : sa) * 32 + l32];
                a0 += bflo(u.x); a1 += bfhi(u.x); a2 += bflo(u.y); a3 += bfhi(u.y);
            }
            for (; k < m; ++k) {                          // single tail (mask hi)
                int s = __builtin_amdgcn_readlane(eid, k);
                uint2 u = Hs2[(size_t)s * 32 + l32];
                if (hi) { u.x = 0; u.y = 0; }
                a0 += bflo(u.x); a1 += bfhi(u.x); a2 += bflo(u.y); a3 += bfhi(u.y);
            }
            for (; k < len; ++k) {                        // deg > 64 fallback (rare)
                int s = ebuf[beg + k];
                uint2 u = Hs2[(size_t)s * 32 + l32];
                if (hi) { u.x = 0; u.y = 0; }
                a0 += bflo(u.x); a1 += bfhi(u.x); a2 += bflo(u.y); a3 += bfhi(u.y);
            }
            if (hi) { usl.x = 0; usl.y = 0; }             // self-loop (mask hi)
            a0 += bflo(usl.x); a1 += bfhi(usl.x); a2 += bflo(usl.y); a3 += bfhi(usl.y);
            // combine halves: every lane ends with the full sums
            a0 += __shfl_xor(a0, 32, 64);
            a1 += __shfl_xor(a1, 32, 64);
            a2 += __shfl_xor(a2, 32, 64);
            a3 += __shfl_xor(a3, 32, 64);
            float wd = inv[node];
            float4 bv = ((const float4*)bias)[l32];
            float o0 = fmaxf(fmaf(wd, a0, bv.x), 0.f);
            float o1 = fmaxf(fmaf(wd, a1, bv.y), 0.f);
            float o2 = fmaxf(fmaf(wd, a2, bv.z), 0.f);
            float o3 = fmaxf(fmaf(wd, a3, bv.w), 0.f);
            if (!hi) {
                tileu[r * 68 + 2 * l32]     = (unsigned int)f2bf(o0) | ((unsigned int)f2bf(o1) << 16);
                tileu[r * 68 + 2 * l32 + 1] = (unsigned int)f2bf(o2) | ((unsigned int)f2bf(o3) << 16);
            }
        } else {
            if (!hi) {
                tileu[r * 68 + 2 * l32] = 0;
                tileu[r * 68 + 2 * l32 + 1] = 0;
            }
        }
    }
    __syncthreads();

    // ---- MFMA phase: wave wid computes 16x16 col-tile wid (cols wid*16..+15)
    int quad = lane >> 4, r16 = lane & 15;
    v4f acc = (v4f){0.f, 0.f, 0.f, 0.f};
#pragma unroll
    for (int kc = 0; kc < 4; ++kc) {
        v8s af = *(const v8s*)&tileu[r16 * 68 + kc * 16 + quad * 4];
        v8s bf = *(const v8s*)(Wt2 + (size_t)(wid * 16 + r16) * 128 + kc * 32 + quad * 8);
        acc = __builtin_amdgcn_mfma_f32_16x16x32_bf16(af, bf, acc, 0, 0, 0);
    }
    float4 iv = ((const float4*)(inv + node0))[quad];
#pragma unroll
    for (int i = 0; i < 4; ++i) {
        int orow = node0 + quad * 4 + i;
        if (orow < n) {
            float sc = (i == 0) ? iv.x : (i == 1) ? iv.y : (i == 2) ? iv.z : iv.w;
            H2[(size_t)orow * 64 + wid * 16 + r16] = f2bf(acc[i] * sc);
        }
    }
}

// ---------------- layer-2 aggregate + bias + log_softmax (2-edge walk) --------
__global__ __launch_bounds__(256) void agg2_final_kernel(
        const unsigned int* __restrict__ Hs,   // h2p as uint [n][32]
        const int* __restrict__ ebuf, const int2* __restrict__ rowpair,
        const float* __restrict__ inv, const float* __restrict__ bp,
        float* __restrict__ outp, int n) {
    int node = __builtin_amdgcn_readfirstlane(blockIdx.x * 4 + (threadIdx.x >> 6));
    int lane = threadIdx.x & 63;
    int l32 = lane & 31;
    bool hi = lane >= 32;
    if (node >= n) return;
    int2 rp = rowpair[node];
    int beg = rp.x, len = rp.y - rp.x;
    int eid = ebuf[beg + lane];
    unsigned int usl = Hs[(size_t)node * 32 + l32];       // self-loop (early)
    int m = len < 64 ? len : 64;
    float ax = 0.f, ay = 0.f;
    int k = 0;
    for (; k + 16 <= m; k += 16) {                        // 16 edges in flight
        int sa0 = __builtin_amdgcn_readlane(eid, k);
        int sb0 = __builtin_amdgcn_readlane(eid, k + 1);
        int sa1 = __builtin_amdgcn_readlane(eid, k + 2);
        int sb1 = __builtin_amdgcn_readlane(eid, k + 3);
        int sa2 = __builtin_amdgcn_readlane(eid, k + 4);
        int sb2 = __builtin_amdgcn_readlane(eid, k + 5);
        int sa3 = __builtin_amdgcn_readlane(eid, k + 6);
        int sb3 = __builtin_amdgcn_readlane(eid, k + 7);
        int sa4 = __builtin_amdgcn_readlane(eid, k + 8);
        int sb4 = __builtin_amdgcn_readlane(eid, k + 9);
        int sa5 = __builtin_amdgcn_readlane(eid, k + 10);
        int sb5 = __builtin_amdgcn_readlane(eid, k + 11);
        int sa6 = __builtin_amdgcn_readlane(eid, k + 12);
        int sb6 = __builtin_amdgcn_readlane(eid, k + 13);
        int sa7 = __builtin_amdgcn_readlane(eid, k + 14);
        int sb7 = __builtin_amdgcn_readlane(eid, k + 15);
        unsigned int u0 = Hs[(size_t)(hi ? sb0 : sa0) * 32 + l32];
        unsigned int u1 = Hs[(size_t)(hi ? sb1 : sa1) * 32 + l32];
        unsigned int u2 = Hs[(size_t)(hi ? sb2 : sa2) * 32 + l32];
        unsigned int u3 = Hs[(size_t)(hi ? sb3 : sa3) * 32 + l32];
        unsigned int u4 = Hs[(size_t)(hi ? sb4 : sa4) * 32 + l32];
        unsigned int u5 = Hs[(size_t)(hi ? sb5 : sa5) * 32 + l32];
        unsigned int u6 = Hs[(size_t)(hi ? sb6 : sa6) * 32 + l32];
        unsigned int u7 = Hs[(size_t)(hi ? sb7 : sa7) * 32 + l32];
        ax += bflo(u0); ay += bfhi(u0);
        ax += bflo(u1); ay += bfhi(u1);
        ax += bflo(u2); ay += bfhi(u2);
        ax += bflo(u3); ay += bfhi(u3);
        ax += bflo(u4); ay += bfhi(u4);
        ax += bflo(u5); ay += bfhi(u5);
        ax += bflo(u6); ay += bfhi(u6);
        ax += bflo(u7); ay += bfhi(u7);
    }
    for (; k + 2 <= m; k += 2) {
        int sa = __builtin_amdgcn_readlane(eid, k);
        int sb = __builtin_amdgcn_readlane(eid, k + 1);
        unsigned int u = Hs[(size_t)(hi ? sb : sa) * 32 + l32];
        ax += bflo(u); ay += bfhi(u);
    }
    for (; k < m; ++k) {
        int s = __builtin_amdgcn_readlane(eid, k);
        unsigned int u = Hs[(size_t)s * 32 + l32];
        if (hi) u = 0;
        ax += bflo(u); ay += bfhi(u);
    }
    for (; k < len; ++k) {                                // deg > 64 fallback
        unsigned int u = Hs[(size_t)ebuf[beg + k] * 32 + l32];
        if (hi) u = 0;
        ax += bflo(u); ay += bfhi(u);
    }
    if (hi) usl = 0;                                      // self-loop
    ax += bflo(usl); ay += bfhi(usl);
    ax += __shfl_xor(ax, 32, 64);
    ay += __shfl_xor(ay, 32, 64);
    float wd = inv[node];
    float2 bv = ((const float2*)bp)[l32];
    float fx = fmaf(wd, ax, bv.x);
    float fy = fmaf(wd, ay, bv.y);
    float mx = fmaxf(fx, fy);
#pragma unroll
    for (int off = 16; off >= 1; off >>= 1) mx = fmaxf(mx, __shfl_xor(mx, off, 64));
    float s = expf(fx - mx) + expf(fy - mx);
#pragma unroll
    for (int off = 16; off >= 1; off >>= 1) s += __shfl_xor(s, off, 64);
    float ls = logf(s);
    if (!hi) {
        ((float2*)(outp + (size_t)node * 64))[l32] = make_float2(fx - mx - ls, fy - mx - ls);
    }
}

static inline size_t align16(size_t x) { return (x + 15) & ~(size_t)15; }

extern "C" void kernel_launch(void* const* d_in, const int* in_sizes, int n_in,
                              void* d_out, int out_size, void* d_ws, size_t ws_size,
                              hipStream_t stream) {
    const float* x    = (const float*)d_in[0];
    const int*   eidx = (const int*)d_in[1];
    const float* W1   = (const float*)d_in[2];
    const float* b1   = (const float*)d_in[3];
    const float* W2   = (const float*)d_in[4];
    const float* b2   = (const float*)d_in[5];
    const float* linW = (const float*)d_in[6];
    const float* linb = (const float*)d_in[7];
    float* out = (float*)d_out;

    const int n = in_sizes[0] / CIN;   // 50000
    const int E = in_sizes[1] / 2;     // 800000
    const int* src = eidx;
    const int* dst = eidx + E;
    const int NBKT = (n + 255) >> 8;   // 196

    // ---- workspace carve-up
    char* ws = (char*)d_ws;
    size_t off = 0;
    int2*  rowpair = (int2*)(ws + off);  off = align16(off + (size_t)n * 8);
    float* inv     = (float*)(ws + off); off = align16(off + (size_t)n * 4);
    int*   bcursor = (int*)(ws + off);   off = align16(off + 256 * 4);
    unsigned short* Wt1 = (unsigned short*)(ws + off); off = align16(off + (size_t)CHID * CIN * 2);
    unsigned short* Wt2 = (unsigned short*)(ws + off); off = align16(off + (size_t)COUT * CHID * 2);
    float* bp      = (float*)(ws + off); off = align16(off + (size_t)COUT * 4);
    unsigned int* binned = (unsigned int*)(ws + off); off = align16(off + (size_t)256 * BCAP * 4);
    int*   ebuf    = (int*)(ws + off);   off = align16(off + (size_t)256 * BCAP * 4);
    unsigned short* h1s = (unsigned short*)(ws + off); off = align16(off + (size_t)n * CHID * 2);
    unsigned short* h2p = (unsigned short*)(ws + off); off = align16(off + (size_t)n * COUT * 2);

    // ---- weight prep + bcursor zeroing
    wprep_kernel<<<CHID + 1, 128, 0, stream>>>(W1, W2, b2, linW, linb, Wt1, Wt2, bp, bcursor);

    // ---- CSR build: bin (fixed-cap regions) -> per-bucket CSR
    bin_kernel<<<(E + BINCHUNK - 1) / BINCHUNK, 256, 0, stream>>>(src, dst, bcursor, binned, E);
    csr_kernel<<<NBKT, 512, 0, stream>>>(binned, bcursor, rowpair, inv, ebuf, n);

    // ---- layer 1: MFMA GEMM
    gemm_mfma<CHID, false><<<(n + 63) / 64, 256, 0, stream>>>(x, Wt1, inv, h1s, n);

    // ---- fused: layer-1 aggregate (+relu+b1) + layer-2 MFMA GEMM (+inv scale)
    agg1_gemm2_kernel<<<(n + 15) / 16, 256, 0, stream>>>((const unsigned int*)h1s, ebuf, rowpair,
                                                         inv, b1, Wt2, h2p, n);

    // ---- layer-2 aggregate + bias + log_softmax
    agg2_final_kernel<<<(n + 3) / 4, 256, 0, stream>>>((const unsigned int*)h2p, ebuf, rowpair,
                                                       inv, bp, out, n);
}

// Round 4
// 201.389 us; speedup vs baseline: 1.1569x; 1.0380x over previous
//
#include <hip/hip_runtime.h>

// GCN forward: fixed-capacity bucket-sort CSR + MFMA GEMMs (bf16, fp32 accum)
// + gather aggregation with PADDED-16 edge walks (8 loads always in flight;
// missing slots padded with the node's own id, corrected by c = 1 - pads).
// gemm2 FUSED into agg1 via an LDS tile (16 nodes/block).
//   W2' = W2 @ (linW_top + linW_bot),  b' = b2 @ (linW_top+linW_bot) + linb
//   h1s[i]  = inv[i] * (x @ W1)[i]                       (bf16, MFMA)
//   agg1[i] = relu( inv[i]*(sum_{N+(i)} h1s[s]) + b1 )   (bf16, in LDS)
//   h2p[i]  = inv[i] * (agg1 @ W2')[i]                   (bf16, MFMA in same kernel)
//   out     = log_softmax( inv[i]*(sum_{N+(i)} h2p[s]) + b' )
// Buckets: 256 dst nodes each, FIXED capacity 8192. n <= 65536 (16-bit src).
// NOTE (round-1 post-mortem): single-pass direct scatter (random 4B writes +
// 800K global atomics) measured 52us vs ~34us for this two-pass build — the
// bucket-localized writes are the point. Do not "simplify" this again.
// NOTE (round-3 post-mortem): FETCH_SIZE 114MB = 8 XCD x 12.8MB h1s is the
// structural miss floor of the random gather; the lever is serial-latency
// elimination (padded walks), not traffic.

#define CIN  128
#define CHID 128
#define COUT 64
#define BCAP_SH 13           // bucket capacity 8192 entries
#define BCAP    (1 << BCAP_SH)
#define BINCHUNK 2048        // small chunks -> 391 blocks -> latency hiding

typedef short v8s __attribute__((ext_vector_type(8)));
typedef float v4f __attribute__((ext_vector_type(4)));

static __device__ __forceinline__ unsigned short f2bf(float f) {
    unsigned int u = __float_as_uint(f);
    unsigned int r = (u + 0x7fffu + ((u >> 16) & 1u)) >> 16;  // RNE
    return (unsigned short)r;
}
static __device__ __forceinline__ float bf2f(unsigned short v) {
    return __uint_as_float(((unsigned int)v) << 16);
}
static __device__ __forceinline__ float bflo(unsigned int u) {
    return __uint_as_float(u << 16);
}
static __device__ __forceinline__ float bfhi(unsigned int u) {
    return __uint_as_float(u & 0xffff0000u);
}

// ---------------- bin edges into fixed-cap bucket regions ----------------
__global__ __launch_bounds__(256) void bin_kernel(const int* __restrict__ src,
                                                  const int* __restrict__ dst,
                                                  int* __restrict__ bcursor,
                                                  unsigned int* __restrict__ binned, int E) {
    __shared__ int h[256];
    __shared__ int base[256];
    int t = threadIdx.x;
    h[t] = 0;
    __syncthreads();
    int e0 = blockIdx.x * BINCHUNK;
    int e1 = e0 + BINCHUNK; if (e1 > E) e1 = E;
    for (int e = e0 + t; e < e1; e += 256)
        atomicAdd(&h[dst[e] >> 8], 1);
    __syncthreads();
    int c = h[t];
    base[t] = (t << BCAP_SH) + (c ? atomicAdd(&bcursor[t], c) : 0);
    __syncthreads();
    h[t] = 0;
    __syncthreads();
    for (int e = e0 + t; e < e1; e += 256) {
        int d = dst[e];
        int b = d >> 8;
        int pos = base[b] + atomicAdd(&h[b], 1);
        binned[pos] = (unsigned int)src[e] | (((unsigned int)d & 255u) << 16);
    }
}

// ---------------- per-bucket CSR build (deg->inv, rowpair, ebuf), 512 thr ------
__global__ __launch_bounds__(512) void csr_kernel(const unsigned int* __restrict__ binned,
                                                  const int* __restrict__ bcursor,
                                                  int2* __restrict__ rowpair,
                                                  float* __restrict__ inv,
                                                  int* __restrict__ ebuf, int n) {
    __shared__ int h[256];
    __shared__ int s[256];
    int b = blockIdx.x;
    int t = threadIdx.x;
    int base = b << BCAP_SH;
    int cnt  = bcursor[b];
    if (t < 256) h[t] = 0;
    __syncthreads();
    for (int i = t; i < cnt; i += 512)
        atomicAdd(&h[binned[base + i] >> 16], 1);
    __syncthreads();
    int myc = (t < 256) ? h[t] : 0;
    if (t < 256) s[t] = myc;
    __syncthreads();
    for (int off = 1; off < 256; off <<= 1) {
        int u = (t >= off && t < 256) ? s[t - off] : 0;
        __syncthreads();
        if (t < 256) s[t] += u;
        __syncthreads();
    }
    if (t < 256) {
        int excl = s[t] - myc;
        int node = (b << 8) + t;
        if (node < n) {
            rowpair[node] = make_int2(base + excl, base + excl + myc);
            inv[node] = rsqrtf((float)(myc + 1));  // +1: self-loop
        }
        h[t] = base + excl;  // cursor
    }
    __syncthreads();
    for (int i = t; i < cnt; i += 512) {
        unsigned int v = binned[base + i];
        int pos = atomicAdd(&h[v >> 16], 1);
        ebuf[pos] = (int)(v & 0xffffu);
    }
}

// ---------------- fused weight prep + bcursor zeroing ----------------
__global__ __launch_bounds__(128) void wprep_kernel(const float* __restrict__ W1,
                                                    const float* __restrict__ W2,
                                                    const float* __restrict__ b2,
                                                    const float* __restrict__ linW,
                                                    const float* __restrict__ linb,
                                                    unsigned short* __restrict__ Wt1,
                                                    unsigned short* __restrict__ Wt2,
                                                    float* __restrict__ bp,
                                                    int* __restrict__ bcursor) {
    int b = blockIdx.x;   // 0..128
    int t = threadIdx.x;  // 0..127
    if (b < CHID) {
        Wt1[b * CIN + t] = f2bf(W1[t * CHID + b]);
        if (t < COUT) {
            float acc = 0.f;
#pragma unroll 8
            for (int k = 0; k < COUT; ++k) {
                float wsv = linW[k * COUT + t] + linW[(k + COUT) * COUT + t];
                acc = fmaf(W2[b * COUT + k], wsv, acc);
            }
            Wt2[t * CHID + b] = f2bf(acc);
        }
    } else {
        bcursor[t] = 0;
        bcursor[128 + t] = 0;
        if (t < COUT) {
            float acc = 0.f;
#pragma unroll 8
            for (int k = 0; k < COUT; ++k) {
                float wsv = linW[k * COUT + t] + linW[(k + COUT) * COUT + t];
                acc = fmaf(b2[k], wsv, acc);
            }
            bp[t] = acc + linb[t];
        }
    }
}

// ---------------- MFMA GEMM: H[i] = inv[i] * (A @ Wt^T)[i], bf16 out ----------
template <int NOUT, bool A_BF16>
__global__ __launch_bounds__(256) void gemm_mfma(const void* __restrict__ Aptr,
                                                 const unsigned short* __restrict__ Wt,
                                                 const float* __restrict__ inv,
                                                 unsigned short* __restrict__ H, int n) {
    constexpr int NCT = NOUT / 16;
    int lane = threadIdx.x & 63;
    int wave = threadIdx.x >> 6;
    int quad = lane >> 4, r16 = lane & 15;
    int row0 = (blockIdx.x * 4 + wave) * 16;
    if (row0 >= n) return;
    int arow = row0 + r16;
    if (arow >= n) arow = n - 1;

    v4f acc[NCT];
#pragma unroll
    for (int c = 0; c < NCT; ++c) acc[c] = (v4f){0.f, 0.f, 0.f, 0.f};

#pragma unroll
    for (int kc = 0; kc < 4; ++kc) {
        v8s af;
        if (A_BF16) {
            const unsigned short* A = (const unsigned short*)Aptr;
            af = *(const v8s*)(A + (size_t)arow * 128 + kc * 32 + quad * 8);
        } else {
            const float* A = (const float*)Aptr;
            const float4* ap = (const float4*)(A + (size_t)arow * 128 + kc * 32 + quad * 8);
            float4 a0 = ap[0], a1 = ap[1];
            af[0] = (short)f2bf(a0.x); af[1] = (short)f2bf(a0.y);
            af[2] = (short)f2bf(a0.z); af[3] = (short)f2bf(a0.w);
            af[4] = (short)f2bf(a1.x); af[5] = (short)f2bf(a1.y);
            af[6] = (short)f2bf(a1.z); af[7] = (short)f2bf(a1.w);
        }
#pragma unroll
        for (int ct = 0; ct < NCT; ++ct) {
            v8s bf = *(const v8s*)(Wt + (size_t)(ct * 16 + r16) * 128 + kc * 32 + quad * 8);
            acc[ct] = __builtin_amdgcn_mfma_f32_16x16x32_bf16(af, bf, acc[ct], 0, 0, 0);
        }
    }

    float4 iv = ((const float4*)(inv + row0))[quad];
#pragma unroll
    for (int ct = 0; ct < NCT; ++ct) {
#pragma unroll
        for (int i = 0; i < 4; ++i) {
            int orow = row0 + quad * 4 + i;
            if (orow < n) {
                float sc = (i == 0) ? iv.x : (i == 1) ? iv.y : (i == 2) ? iv.z : iv.w;
                H[(size_t)orow * NOUT + ct * 16 + r16] = f2bf(acc[ct][i] * sc);
            }
        }
    }
}

// ---------------- FUSED layer-1 aggregate + layer-2 GEMM ----------------
// Block = 256 thr = 4 waves = 16 nodes. Wave preloads all 4 nodes' state,
// then per node walks ceil(deg/16) PADDED-16 blocks (8 uint2 loads in
// flight; pad slots load the node's own hot row, corrected by c = 1-pads).
__global__ __launch_bounds__(256) void agg1_gemm2_kernel(
        const unsigned int* __restrict__ Hs,      // h1s as uint [n][64]
        const int* __restrict__ ebuf,
        const int2* __restrict__ rowpair,
        const float* __restrict__ inv,
        const float* __restrict__ bias,           // b1[128]
        const unsigned short* __restrict__ Wt2,   // [64][128] bf16
        unsigned short* __restrict__ H2,          // h2p [n][64]
        int n) {
    __shared__ unsigned int tileu[16 * 68];
    const uint2* __restrict__ Hs2 = (const uint2*)Hs;  // [n][32] uint2
    int node0 = blockIdx.x * 16;
    int wid = __builtin_amdgcn_readfirstlane(threadIdx.x >> 6);
    int lane = threadIdx.x & 63;
    int l32 = lane & 31;
    bool hi = lane >= 32;

    // hoisted preloads for the wave's 4 nodes (all loads in flight together)
    int nodes[4], begs[4], lens[4], eids[4];
    uint2 usls[4];
    float invs[4];
#pragma unroll
    for (int j = 0; j < 4; ++j) {
        int node = node0 + wid * 4 + j;
        if (node >= n) node = n - 1;              // n%16==0 here; safety clamp
        nodes[j] = node;
        int2 rp = rowpair[node];
        begs[j] = rp.x;
        lens[j] = rp.y - rp.x;
        eids[j] = ebuf[rp.x + lane];
        usls[j] = Hs2[(size_t)node * 32 + l32];
        invs[j] = inv[node];
    }

#pragma unroll
    for (int j = 0; j < 4; ++j) {
        int node = nodes[j];
        int beg = begs[j], len = lens[j];
        int eid = eids[j];
        uint2 usl = usls[j];
        int r = wid * 4 + j;
        int m = len < 64 ? len : 64;
        int kmax = (m + 15) & ~15;
        int padi = kmax - m;                      // # self-pad slots (scalar)
        float a0 = 0.f, a1 = 0.f, a2 = 0.f, a3 = 0.f;
        for (int k = 0; k < kmax; k += 16) {      // padded-16: 8 loads in flight
            int s0  = (k +  0 < m) ? __builtin_amdgcn_readlane(eid, k +  0) : node;
            int s1  = (k +  1 < m) ? __builtin_amdgcn_readlane(eid, (k +  1) & 63) : node;
            int s2  = (k +  2 < m) ? __builtin_amdgcn_readlane(eid, (k +  2) & 63) : node;
            int s3  = (k +  3 < m) ? __builtin_amdgcn_readlane(eid, (k +  3) & 63) : node;
            int s4  = (k +  4 < m) ? __builtin_amdgcn_readlane(eid, (k +  4) & 63) : node;
            int s5  = (k +  5 < m) ? __builtin_amdgcn_readlane(eid, (k +  5) & 63) : node;
            int s6  = (k +  6 < m) ? __builtin_amdgcn_readlane(eid, (k +  6) & 63) : node;
            int s7  = (k +  7 < m) ? __builtin_amdgcn_readlane(eid, (k +  7) & 63) : node;
            int s8  = (k +  8 < m) ? __builtin_amdgcn_readlane(eid, (k +  8) & 63) : node;
            int s9  = (k +  9 < m) ? __builtin_amdgcn_readlane(eid, (k +  9) & 63) : node;
            int s10 = (k + 10 < m) ? __builtin_amdgcn_readlane(eid, (k + 10) & 63) : node;
            int s11 = (k + 11 < m) ? __builtin_amdgcn_readlane(eid, (k + 11) & 63) : node;
            int s12 = (k + 12 < m) ? __builtin_amdgcn_readlane(eid, (k + 12) & 63) : node;
            int s13 = (k + 13 < m) ? __builtin_amdgcn_readlane(eid, (k + 13) & 63) : node;
            int s14 = (k + 14 < m) ? __builtin_amdgcn_readlane(eid, (k + 14) & 63) : node;
            int s15 = (k + 15 < m) ? __builtin_amdgcn_readlane(eid, (k + 15) & 63) : node;
            uint2 u0 = Hs2[(size_t)(hi ? s1  : s0)  * 32 + l32];
            uint2 u1 = Hs2[(size_t)(hi ? s3  : s2)  * 32 + l32];
            uint2 u2 = Hs2[(size_t)(hi ? s5  : s4)  * 32 + l32];
            uint2 u3 = Hs2[(size_t)(hi ? s7  : s6)  * 32 + l32];
            uint2 u4 = Hs2[(size_t)(hi ? s9  : s8)  * 32 + l32];
            uint2 u5 = Hs2[(size_t)(hi ? s11 : s10) * 32 + l32];
            uint2 u6 = Hs2[(size_t)(hi ? s13 : s12) * 32 + l32];
            uint2 u7 = Hs2[(size_t)(hi ? s15 : s14) * 32 + l32];
            a0 += bflo(u0.x); a1 += bfhi(u0.x); a2 += bflo(u0.y); a3 += bfhi(u0.y);
            a0 += bflo(u1.x); a1 += bfhi(u1.x); a2 += bflo(u1.y); a3 += bfhi(u1.y);
            a0 += bflo(u2.x); a1 += bfhi(u2.x); a2 += bflo(u2.y); a3 += bfhi(u2.y);
            a0 += bflo(u3.x); a1 += bfhi(u3.x); a2 += bflo(u3.y); a3 += bfhi(u3.y);
            a0 += bflo(u4.x); a1 += bfhi(u4.x); a2 += bflo(u4.y); a3 += bfhi(u4.y);
            a0 += bflo(u5.x); a1 += bfhi(u5.x); a2 += bflo(u5.y); a3 += bfhi(u5.y);
            a0 += bflo(u6.x); a1 += bfhi(u6.x); a2 += bflo(u6.y); a3 += bfhi(u6.y);
            a0 += bflo(u7.x); a1 += bfhi(u7.x); a2 += bflo(u7.y); a3 += bfhi(u7.y);
        }
        for (int k = 64; k < len; ++k) {          // deg > 64 fallback (rare)
            int s = ebuf[beg + k];
            uint2 u = Hs2[(size_t)s * 32 + l32];
            if (hi) { u.x = 0; u.y = 0; }
            a0 += bflo(u.x); a1 += bfhi(u.x); a2 += bflo(u.y); a3 += bfhi(u.y);
        }
        // self-loop + pad correction: walk added padi self rows; want exactly 1.
        float c = 1.0f - (float)padi;
        if (hi) { usl.x = 0; usl.y = 0; }
        a0 = fmaf(c, bflo(usl.x), a0); a1 = fmaf(c, bfhi(usl.x), a1);
        a2 = fmaf(c, bflo(usl.y), a2); a3 = fmaf(c, bfhi(usl.y), a3);
        // combine halves
        a0 += __shfl_xor(a0, 32, 64);
        a1 += __shfl_xor(a1, 32, 64);
        a2 += __shfl_xor(a2, 32, 64);
        a3 += __shfl_xor(a3, 32, 64);
        float wd = invs[j];
        float4 bv = ((const float4*)bias)[l32];
        float o0 = fmaxf(fmaf(wd, a0, bv.x), 0.f);
        float o1 = fmaxf(fmaf(wd, a1, bv.y), 0.f);
        float o2 = fmaxf(fmaf(wd, a2, bv.z), 0.f);
        float o3 = fmaxf(fmaf(wd, a3, bv.w), 0.f);
        if (!hi) {
            tileu[r * 68 + 2 * l32]     = (unsigned int)f2bf(o0) | ((unsigned int)f2bf(o1) << 16);
            tileu[r * 68 + 2 * l32 + 1] = (unsigned int)f2bf(o2) | ((unsigned int)f2bf(o3) << 16);
        }
    }
    __syncthreads();

    // ---- MFMA phase: wave wid computes 16x16 col-tile wid (cols wid*16..+15)
    int quad = lane >> 4, r16 = lane & 15;
    v4f acc = (v4f){0.f, 0.f, 0.f, 0.f};
#pragma unroll
    for (int kc = 0; kc < 4; ++kc) {
        v8s af = *(const v8s*)&tileu[r16 * 68 + kc * 16 + quad * 4];
        v8s bf = *(const v8s*)(Wt2 + (size_t)(wid * 16 + r16) * 128 + kc * 32 + quad * 8);
        acc = __builtin_amdgcn_mfma_f32_16x16x32_bf16(af, bf, acc, 0, 0, 0);
    }
    float4 iv = ((const float4*)(inv + node0))[quad];
#pragma unroll
    for (int i = 0; i < 4; ++i) {
        int orow = node0 + quad * 4 + i;
        if (orow < n) {
            float sc = (i == 0) ? iv.x : (i == 1) ? iv.y : (i == 2) ? iv.z : iv.w;
            H2[(size_t)orow * 64 + wid * 16 + r16] = f2bf(acc[i] * sc);
        }
    }
}

// ---------------- layer-2 aggregate + bias + log_softmax (padded-16 walk) -----
__global__ __launch_bounds__(256) void agg2_final_kernel(
        const unsigned int* __restrict__ Hs,   // h2p as uint [n][32]
        const int* __restrict__ ebuf, const int2* __restrict__ rowpair,
        const float* __restrict__ inv, const float* __restrict__ bp,
        float* __restrict__ outp, int n) {
    int node = __builtin_amdgcn_readfirstlane(blockIdx.x * 4 + (threadIdx.x >> 6));
    int lane = threadIdx.x & 63;
    int l32 = lane & 31;
    bool hi = lane >= 32;
    if (node >= n) return;
    int2 rp = rowpair[node];
    int beg = rp.x, len = rp.y - rp.x;
    int eid = ebuf[beg + lane];
    unsigned int usl = Hs[(size_t)node * 32 + l32];       // self-loop (early)
    int m = len < 64 ? len : 64;
    int kmax = (m + 15) & ~15;
    int padi = kmax - m;
    float ax = 0.f, ay = 0.f;
    for (int k = 0; k < kmax; k += 16) {                  // padded-16 walk
        int s0  = (k +  0 < m) ? __builtin_amdgcn_readlane(eid, k +  0) : node;
        int s1  = (k +  1 < m) ? __builtin_amdgcn_readlane(eid, (k +  1) & 63) : node;
        int s2  = (k +  2 < m) ? __builtin_amdgcn_readlane(eid, (k +  2) & 63) : node;
        int s3  = (k +  3 < m) ? __builtin_amdgcn_readlane(eid, (k +  3) & 63) : node;
        int s4  = (k +  4 < m) ? __builtin_amdgcn_readlane(eid, (k +  4) & 63) : node;
        int s5  = (k +  5 < m) ? __builtin_amdgcn_readlane(eid, (k +  5) & 63) : node;
        int s6  = (k +  6 < m) ? __builtin_amdgcn_readlane(eid, (k +  6) & 63) : node;
        int s7  = (k +  7 < m) ? __builtin_amdgcn_readlane(eid, (k +  7) & 63) : node;
        int s8  = (k +  8 < m) ? __builtin_amdgcn_readlane(eid, (k +  8) & 63) : node;
        int s9  = (k +  9 < m) ? __builtin_amdgcn_readlane(eid, (k +  9) & 63) : node;
        int s10 = (k + 10 < m) ? __builtin_amdgcn_readlane(eid, (k + 10) & 63) : node;
        int s11 = (k + 11 < m) ? __builtin_amdgcn_readlane(eid, (k + 11) & 63) : node;
        int s12 = (k + 12 < m) ? __builtin_amdgcn_readlane(eid, (k + 12) & 63) : node;
        int s13 = (k + 13 < m) ? __builtin_amdgcn_readlane(eid, (k + 13) & 63) : node;
        int s14 = (k + 14 < m) ? __builtin_amdgcn_readlane(eid, (k + 14) & 63) : node;
        int s15 = (k + 15 < m) ? __builtin_amdgcn_readlane(eid, (k + 15) & 63) : node;
        unsigned int u0 = Hs[(size_t)(hi ? s1  : s0)  * 32 + l32];
        unsigned int u1 = Hs[(size_t)(hi ? s3  : s2)  * 32 + l32];
        unsigned int u2 = Hs[(size_t)(hi ? s5  : s4)  * 32 + l32];
        unsigned int u3 = Hs[(size_t)(hi ? s7  : s6)  * 32 + l32];
        unsigned int u4 = Hs[(size_t)(hi ? s9  : s8)  * 32 + l32];
        unsigned int u5 = Hs[(size_t)(hi ? s11 : s10) * 32 + l32];
        unsigned int u6 = Hs[(size_t)(hi ? s13 : s12) * 32 + l32];
        unsigned int u7 = Hs[(size_t)(hi ? s15 : s14) * 32 + l32];
        ax += bflo(u0); ay += bfhi(u0);
        ax += bflo(u1); ay += bfhi(u1);
        ax += bflo(u2); ay += bfhi(u2);
        ax += bflo(u3); ay += bfhi(u3);
        ax += bflo(u4); ay += bfhi(u4);
        ax += bflo(u5); ay += bfhi(u5);
        ax += bflo(u6); ay += bfhi(u6);
        ax += bflo(u7); ay += bfhi(u7);
    }
    for (int k = 64; k < len; ++k) {                      // deg > 64 fallback
        unsigned int u = Hs[(size_t)ebuf[beg + k] * 32 + l32];
        if (hi) u = 0;
        ax += bflo(u); ay += bfhi(u);
    }
    float c = 1.0f - (float)padi;                         // self + pad correction
    if (hi) usl = 0;
    ax = fmaf(c, bflo(usl), ax);
    ay = fmaf(c, bfhi(usl), ay);
    ax += __shfl_xor(ax, 32, 64);
    ay += __shfl_xor(ay, 32, 64);
    float wd = inv[node];
    float2 bv = ((const float2*)bp)[l32];
    float fx = fmaf(wd, ax, bv.x);
    float fy = fmaf(wd, ay, bv.y);
    float mx = fmaxf(fx, fy);
#pragma unroll
    for (int off = 16; off >= 1; off >>= 1) mx = fmaxf(mx, __shfl_xor(mx, off, 64));
    float s = expf(fx - mx) + expf(fy - mx);
#pragma unroll
    for (int off = 16; off >= 1; off >>= 1) s += __shfl_xor(s, off, 64);
    float ls = logf(s);
    if (!hi) {
        ((float2*)(outp + (size_t)node * 64))[l32] = make_float2(fx - mx - ls, fy - mx - ls);
    }
}

static inline size_t align16(size_t x) { return (x + 15) & ~(size_t)15; }

extern "C" void kernel_launch(void* const* d_in, const int* in_sizes, int n_in,
                              void* d_out, int out_size, void* d_ws, size_t ws_size,
                              hipStream_t stream) {
    const float* x    = (const float*)d_in[0];
    const int*   eidx = (const int*)d_in[1];
    const float* W1   = (const float*)d_in[2];
    const float* b1   = (const float*)d_in[3];
    const float* W2   = (const float*)d_in[4];
    const float* b2   = (const float*)d_in[5];
    const float* linW = (const float*)d_in[6];
    const float* linb = (const float*)d_in[7];
    float* out = (float*)d_out;

    const int n = in_sizes[0] / CIN;   // 50000
    const int E = in_sizes[1] / 2;     // 800000
    const int* src = eidx;
    const int* dst = eidx + E;
    const int NBKT = (n + 255) >> 8;   // 196

    // ---- workspace carve-up
    char* ws = (char*)d_ws;
    size_t off = 0;
    int2*  rowpair = (int2*)(ws + off);  off = align16(off + (size_t)n * 8);
    float* inv     = (float*)(ws + off); off = align16(off + (size_t)n * 4);
    int*   bcursor = (int*)(ws + off);   off = align16(off + 256 * 4);
    unsigned short* Wt1 = (unsigned short*)(ws + off); off = align16(off + (size_t)CHID * CIN * 2);
    unsigned short* Wt2 = (unsigned short*)(ws + off); off = align16(off + (size_t)COUT * CHID * 2);
    float* bp      = (float*)(ws + off); off = align16(off + (size_t)COUT * 4);
    unsigned int* binned = (unsigned int*)(ws + off); off = align16(off + (size_t)256 * BCAP * 4);
    int*   ebuf    = (int*)(ws + off);   off = align16(off + (size_t)256 * BCAP * 4);
    unsigned short* h1s = (unsigned short*)(ws + off); off = align16(off + (size_t)n * CHID * 2);
    unsigned short* h2p = (unsigned short*)(ws + off); off = align16(off + (size_t)n * COUT * 2);

    // ---- weight prep + bcursor zeroing
    wprep_kernel<<<CHID + 1, 128, 0, stream>>>(W1, W2, b2, linW, linb, Wt1, Wt2, bp, bcursor);

    // ---- CSR build: bin (fixed-cap regions) -> per-bucket CSR
    bin_kernel<<<(E + BINCHUNK - 1) / BINCHUNK, 256, 0, stream>>>(src, dst, bcursor, binned, E);
    csr_kernel<<<NBKT, 512, 0, stream>>>(binned, bcursor, rowpair, inv, ebuf, n);

    // ---- layer 1: MFMA GEMM
    gemm_mfma<CHID, false><<<(n + 63) / 64, 256, 0, stream>>>(x, Wt1, inv, h1s, n);

    // ---- fused: layer-1 aggregate (+relu+b1) + layer-2 MFMA GEMM (+inv scale)
    agg1_gemm2_kernel<<<(n + 15) / 16, 256, 0, stream>>>((const unsigned int*)h1s, ebuf, rowpair,
                                                         inv, b1, Wt2, h2p, n);

    // ---- layer-2 aggregate + bias + log_softmax
    agg2_final_kernel<<<(n + 3) / 4, 256, 0, stream>>>((const unsigned int*)h2p, ebuf, rowpair,
                                                       inv, bp, out, n);
}